// Round 1
// baseline (84.000 us; speedup 1.0000x reference)
//
#include <hip/hip_runtime.h>
#include <hip/hip_bf16.h>

#define T_LEN 2048
#define D_DIM 128
#define K_DIM 2048
#define M_DIM 8192
#define LOOKUP 101
#define HWIN 50

typedef __attribute__((ext_vector_type(8))) short short8;
typedef __attribute__((ext_vector_type(4))) float f32x4;

static __device__ __forceinline__ unsigned int f2bf(float f) {
  unsigned int u = __float_as_uint(f);
  return (u + 0x7fffu + ((u >> 16) & 1u)) >> 16;  // RNE bf16 bits
}
static __device__ __forceinline__ float bflo(unsigned int u) { return __uint_as_float(u << 16); }
static __device__ __forceinline__ float bfhi(unsigned int u) { return __uint_as_float(u & 0xffff0000u); }

// ---------------- Kernel 1: W [2048][128] f32 -> Wt [128][2048] bf16 ----------------
__global__ __launch_bounds__(256) void k_wt(const float* __restrict__ W,
                                            unsigned short* __restrict__ Wt) {
  __shared__ float tile[64][65];
  const int kb = blockIdx.x;  // 0..31
  const int db = blockIdx.y;  // 0..1
  const int t = threadIdx.x;
#pragma unroll
  for (int j = 0; j < 4; ++j) {
    int idx4 = t + j * 256;          // 0..1023 float4s of the 64x64 tile
    int r = idx4 >> 4, c = (idx4 & 15) * 4;
    float4 v = *(const float4*)(W + (kb * 64 + r) * D_DIM + db * 64 + c);
    tile[r][c + 0] = v.x; tile[r][c + 1] = v.y; tile[r][c + 2] = v.z; tile[r][c + 3] = v.w;
  }
  __syncthreads();
  const int d = t >> 2, kq = t & 3;  // out row d (0..63), 16-k chunk
  unsigned int pk[8];
#pragma unroll
  for (int i = 0; i < 8; ++i) {
    unsigned int lo = f2bf(tile[kq * 16 + 2 * i][d]);
    unsigned int hi = f2bf(tile[kq * 16 + 2 * i + 1][d]);
    pk[i] = lo | (hi << 16);
  }
  unsigned short* dst = Wt + (db * 64 + d) * K_DIM + kb * 64 + kq * 16;
  *(uint4*)dst = make_uint4(pk[0], pk[1], pk[2], pk[3]);
  *(uint4*)(dst + 8) = make_uint4(pk[4], pk[5], pk[6], pk[7]);
}

// ---------------- Kernel 2: p = x@W + b, row-normalize, store bf16 ----------------
// BM=32 rows/block, BK=64. 4 waves: wave = (rt = w&1 row-tile of 16, ch = w>>1 col-half of 64)
#define BM 32
#define BK 64
#define NKT (K_DIM / BK)

__global__ __launch_bounds__(256) void k_gemm(const float* __restrict__ X,
                                              const unsigned short* __restrict__ Wt,
                                              const float* __restrict__ bias,
                                              unsigned short* __restrict__ Pn) {
  __shared__ unsigned short As[2][BM * BK];    // [row][k] swizzled, 8 KiB
  __shared__ unsigned short Bs[2][D_DIM * BK]; // [col][k] swizzled, 32 KiB
  __shared__ float Pt[BM][D_DIM];              // epilogue, 16 KiB

  const int tid = threadIdx.x;
  const int m0 = blockIdx.x * BM;
  const int lane = tid & 63;
  const int wv = tid >> 6;
  const int rt = wv & 1;
  const int ch = wv >> 1;

  // A staging: thread -> (row ar, k-group akg of 8)
  const int ar = tid >> 3, akg = tid & 7;
  const float* aptr = X + (size_t)(m0 + ar) * K_DIM + akg * 8;
  const int aidx = ar * BK + ((akg ^ (ar & 7)) << 3);
  // B staging: thread -> (col bd, half bh of 32 k)
  const int bd = tid >> 1, bh = tid & 1;
  const unsigned short* bptr = Wt + (size_t)bd * K_DIM + bh * 32;

  float4 a0, a1;
  uint4 brg[4];

  auto load_regs = [&](int kt) {
    a0 = *(const float4*)(aptr + kt * BK);
    a1 = *(const float4*)(aptr + kt * BK + 4);
#pragma unroll
    for (int g = 0; g < 4; ++g)
      brg[g] = *(const uint4*)(bptr + kt * BK + g * 8);
  };
  auto write_lds = [&](int buf) {
    uint4 av;
    av.x = f2bf(a0.x) | (f2bf(a0.y) << 16);
    av.y = f2bf(a0.z) | (f2bf(a0.w) << 16);
    av.z = f2bf(a1.x) | (f2bf(a1.y) << 16);
    av.w = f2bf(a1.z) | (f2bf(a1.w) << 16);
    *(uint4*)&As[buf][aidx] = av;
#pragma unroll
    for (int g = 0; g < 4; ++g) {
      int gg = bh * 4 + g;
      *(uint4*)&Bs[buf][bd * BK + ((gg ^ (bd & 7)) << 3)] = brg[g];
    }
  };

  f32x4 acc[4];
#pragma unroll
  for (int i = 0; i < 4; ++i) acc[i] = (f32x4){0.f, 0.f, 0.f, 0.f};

  const int arow = rt * 16 + (lane & 15);
  const int abase = arow * BK;
  int cbase[4];
#pragma unroll
  for (int nt = 0; nt < 4; ++nt) {
    int col = ch * 64 + nt * 16 + (lane & 15);
    cbase[nt] = col * BK + ((col & 7) << 3);  // xor applied to kgrp below via ^ pattern
  }
  const int kg_lane = (lane >> 4);  // 0..3

  load_regs(0);
  write_lds(0);
  __syncthreads();
  int cur = 0;
  for (int kt = 0; kt < NKT; ++kt) {
    if (kt + 1 < NKT) load_regs(kt + 1);
#pragma unroll
    for (int kk = 0; kk < 2; ++kk) {
      int kgrp = kk * 4 + kg_lane;  // group-of-8 within BK row
      short8 af = *(const short8*)&As[cur][abase + ((kgrp ^ (arow & 7)) << 3)];
#pragma unroll
      for (int nt = 0; nt < 4; ++nt) {
        int col = ch * 64 + nt * 16 + (lane & 15);
        short8 bfr = *(const short8*)&Bs[cur][col * BK + ((kgrp ^ (col & 7)) << 3)];
        acc[nt] = __builtin_amdgcn_mfma_f32_16x16x32_bf16(af, bfr, acc[nt], 0, 0, 0);
      }
    }
    __syncthreads();
    if (kt + 1 < NKT) write_lds(cur ^ 1);
    __syncthreads();
    cur ^= 1;
  }

  // epilogue: acc -> Pt with bias
#pragma unroll
  for (int nt = 0; nt < 4; ++nt) {
    int col = ch * 64 + nt * 16 + (lane & 15);
    float bv = bias[col];
#pragma unroll
    for (int r = 0; r < 4; ++r) {
      int row = rt * 16 + (lane >> 4) * 4 + r;
      Pt[row][col] = acc[nt][r] + bv;
    }
  }
  __syncthreads();

  // normalize: 8 threads per row, 16 cols each
  const int nr = tid >> 3;
  const int c0 = (tid & 7) * 16;
  float4 v[4];
  float ss = 0.f;
#pragma unroll
  for (int j = 0; j < 4; ++j) {
    v[j] = *(float4*)&Pt[nr][c0 + j * 4];
    ss += v[j].x * v[j].x + v[j].y * v[j].y + v[j].z * v[j].z + v[j].w * v[j].w;
  }
  ss += __shfl_xor(ss, 1);
  ss += __shfl_xor(ss, 2);
  ss += __shfl_xor(ss, 4);
  float s = 1.0f / fmaxf(sqrtf(ss), 1e-12f);
  unsigned int pk[8];
#pragma unroll
  for (int j = 0; j < 4; ++j) {
    pk[2 * j] = f2bf(v[j].x * s) | (f2bf(v[j].y * s) << 16);
    pk[2 * j + 1] = f2bf(v[j].z * s) | (f2bf(v[j].w * s) << 16);
  }
  unsigned short* dst = Pn + (size_t)(m0 + nr) * D_DIM + c0;
  *(uint4*)dst = make_uint4(pk[0], pk[1], pk[2], pk[3]);
  *(uint4*)(dst + 8) = make_uint4(pk[4], pk[5], pk[6], pk[7]);
}

// ---------------- Kernel 3: banded similarity ----------------
#define TR 32
#define LROWS 136  // 50 + 32 + 50 = 132, padded (rows 132..135 zero)

__global__ __launch_bounds__(256) void k_sim(const unsigned short* __restrict__ Pn,
                                             float* __restrict__ out) {
  __shared__ unsigned short sm[LROWS * D_DIM];
  const int bb = blockIdx.x >> 6;   // batch
  const int tb = blockIdx.x & 63;   // tile within batch
  const int t0 = tb * TR;
  const int tid = threadIdx.x;

  // load rows t0-50 .. t0+81 (zero outside [0,T)), XOR-swizzled by ((i>>2)&15)
  for (int idx = tid; idx < LROWS * 16; idx += 256) {
    int i = idx >> 4, seg = idx & 15;
    int t = t0 - HWIN + i;
    uint4 val = make_uint4(0u, 0u, 0u, 0u);
    if (i < 132 && t >= 0 && t < T_LEN)
      val = *(const uint4*)(Pn + ((size_t)bb * T_LEN + t) * D_DIM + seg * 8);
    *(uint4*)&sm[i * D_DIM + ((seg ^ ((i >> 2) & 15)) << 3)] = val;
  }
  __syncthreads();

  for (int u = tid; u < TR * 26; u += 256) {
    int r = u / 26;
    int w0 = (u - r * 26) * 4;
    float acc[4] = {0.f, 0.f, 0.f, 0.f};
    const int qrow = r + HWIN;
#pragma unroll 4
    for (int dc = 0; dc < 16; ++dc) {
      uint4 q = *(const uint4*)&sm[qrow * D_DIM + ((dc ^ ((qrow >> 2) & 15)) << 3)];
      float qf0 = bflo(q.x), qf1 = bfhi(q.x), qf2 = bflo(q.y), qf3 = bfhi(q.y);
      float qf4 = bflo(q.z), qf5 = bfhi(q.z), qf6 = bflo(q.w), qf7 = bfhi(q.w);
#pragma unroll
      for (int j = 0; j < 4; ++j) {
        int wr = r + w0 + j;
        uint4 wv = *(const uint4*)&sm[wr * D_DIM + ((dc ^ ((wr >> 2) & 15)) << 3)];
        acc[j] += qf0 * bflo(wv.x) + qf1 * bfhi(wv.x) + qf2 * bflo(wv.y) + qf3 * bfhi(wv.y) +
                  qf4 * bflo(wv.z) + qf5 * bfhi(wv.z) + qf6 * bflo(wv.w) + qf7 * bfhi(wv.w);
      }
    }
    float* op = out + ((size_t)bb * T_LEN + t0 + r) * LOOKUP + w0;
#pragma unroll
    for (int j = 0; j < 4; ++j)
      if (w0 + j < LOOKUP) op[j] = acc[j];
  }
}

extern "C" void kernel_launch(void* const* d_in, const int* in_sizes, int n_in,
                              void* d_out, int out_size, void* d_ws, size_t ws_size,
                              hipStream_t stream) {
  (void)in_sizes; (void)n_in; (void)out_size; (void)ws_size;
  const float* x = (const float*)d_in[0];
  const float* W = (const float*)d_in[1];
  const float* b = (const float*)d_in[2];
  float* out = (float*)d_out;
  unsigned short* Wt = (unsigned short*)d_ws;            // 128*2048 bf16 = 512 KiB
  unsigned short* Pn = Wt + (size_t)D_DIM * K_DIM;       // 8192*128 bf16 = 2 MiB

  k_wt<<<dim3(32, 2), 256, 0, stream>>>(W, Wt);
  k_gemm<<<M_DIM / BM, 256, 0, stream>>>(x, Wt, b, Pn);
  k_sim<<<4 * (T_LEN / TR), 256, 0, stream>>>(Pn, out);
}

// Round 2
// 72.890 us; speedup vs baseline: 1.1524x; 1.1524x over previous
//
#include <hip/hip_runtime.h>
#include <hip/hip_bf16.h>

#define T_LEN 2048
#define D_DIM 128
#define K_DIM 2048
#define M_DIM 8192
#define LOOKUP 101
#define HWIN 50

typedef __attribute__((ext_vector_type(8))) short short8;
typedef __attribute__((ext_vector_type(4))) float f32x4;

static __device__ __forceinline__ unsigned int f2bf(float f) {
  unsigned int u = __float_as_uint(f);
  return (u + 0x7fffu + ((u >> 16) & 1u)) >> 16;  // RNE bf16 bits
}
static __device__ __forceinline__ float bflo(unsigned int u) { return __uint_as_float(u << 16); }
static __device__ __forceinline__ float bfhi(unsigned int u) { return __uint_as_float(u & 0xffff0000u); }

static __device__ __forceinline__ short8 pack8(float4 lo, float4 hi) {
  uint4 u;
  u.x = f2bf(lo.x) | (f2bf(lo.y) << 16);
  u.y = f2bf(lo.z) | (f2bf(lo.w) << 16);
  u.z = f2bf(hi.x) | (f2bf(hi.y) << 16);
  u.w = f2bf(hi.z) | (f2bf(hi.w) << 16);
  return *(short8*)&u;
}

// ---------------- Kernel 1: W [2048][128] f32 -> Wt [128][2048] bf16 ----------------
__global__ __launch_bounds__(256) void k_wt(const float* __restrict__ W,
                                            unsigned short* __restrict__ Wt) {
  __shared__ float tile[64][65];
  const int kb = blockIdx.x;  // 0..31
  const int db = blockIdx.y;  // 0..1
  const int t = threadIdx.x;
#pragma unroll
  for (int j = 0; j < 4; ++j) {
    int idx4 = t + j * 256;          // 0..1023 float4s of the 64x64 tile
    int r = idx4 >> 4, c = (idx4 & 15) * 4;
    float4 v = *(const float4*)(W + (kb * 64 + r) * D_DIM + db * 64 + c);
    tile[r][c + 0] = v.x; tile[r][c + 1] = v.y; tile[r][c + 2] = v.z; tile[r][c + 3] = v.w;
  }
  __syncthreads();
  const int d = t >> 2, kq = t & 3;  // out row d (0..63), 16-k chunk
  unsigned int pk[8];
#pragma unroll
  for (int i = 0; i < 8; ++i) {
    unsigned int lo = f2bf(tile[kq * 16 + 2 * i][d]);
    unsigned int hi = f2bf(tile[kq * 16 + 2 * i + 1][d]);
    pk[i] = lo | (hi << 16);
  }
  unsigned short* dst = Wt + (db * 64 + d) * K_DIM + kb * 64 + kq * 16;
  *(uint4*)dst = make_uint4(pk[0], pk[1], pk[2], pk[3]);
  *(uint4*)(dst + 8) = make_uint4(pk[4], pk[5], pk[6], pk[7]);
}

// ---------------- Kernel 2: barrier-free skinny GEMM + fused bias/norm ----------------
// 1 wave per block. Wave owns 16 rows x 128 cols x K=2048. No LDS, no barriers.
// A from global f32 (converted in-reg), B from L2-resident Wt. 1-stage register pipeline.

#define LOAD_STAGE(A0, A1, A2, A3, BV, kk)                                       \
  A0 = *(const float4*)(aptr + (kk));                                            \
  A1 = *(const float4*)(aptr + (kk) + 4);                                        \
  A2 = *(const float4*)(aptr + (kk) + 32);                                       \
  A3 = *(const float4*)(aptr + (kk) + 36);                                       \
  _Pragma("unroll") for (int ct = 0; ct < 8; ++ct) {                             \
    BV[ct] = *(const short8*)(bptr + (size_t)ct * 16 * K_DIM + (kk));            \
    BV[ct + 8] = *(const short8*)(bptr + (size_t)ct * 16 * K_DIM + (kk) + 32);   \
  }

#define MFMA_STAGE(A0, A1, A2, A3, BV)                                           \
  {                                                                              \
    short8 af0 = pack8(A0, A1);                                                  \
    short8 af1 = pack8(A2, A3);                                                  \
    _Pragma("unroll") for (int ct = 0; ct < 8; ++ct)                             \
        acc[ct] = __builtin_amdgcn_mfma_f32_16x16x32_bf16(af0, BV[ct], acc[ct], 0, 0, 0); \
    _Pragma("unroll") for (int ct = 0; ct < 8; ++ct)                             \
        acc[ct] = __builtin_amdgcn_mfma_f32_16x16x32_bf16(af1, BV[ct + 8], acc[ct], 0, 0, 0); \
  }

__global__ __launch_bounds__(64, 2) void k_gemm(const float* __restrict__ X,
                                                const unsigned short* __restrict__ Wt,
                                                const float* __restrict__ bias,
                                                unsigned short* __restrict__ Pn) {
  const int lane = threadIdx.x & 63;
  const int r0 = blockIdx.x * 16;  // grid = 512
  const int l15 = lane & 15;
  const int kg = lane >> 4;  // 0..3

  const float* aptr = X + (size_t)(r0 + l15) * K_DIM + kg * 8;
  const unsigned short* bptr = Wt + (size_t)l15 * K_DIM + kg * 8;

  f32x4 acc[8];
#pragma unroll
  for (int i = 0; i < 8; ++i) acc[i] = (f32x4){0.f, 0.f, 0.f, 0.f};

  float4 p0, p1, p2, p3, q0, q1, q2, q3;
  short8 b0[16], b1[16];

  LOAD_STAGE(p0, p1, p2, p3, b0, 0)
  for (int k = 0; k < K_DIM - 128; k += 128) {
    LOAD_STAGE(q0, q1, q2, q3, b1, k + 64)
    MFMA_STAGE(p0, p1, p2, p3, b0)
    LOAD_STAGE(p0, p1, p2, p3, b0, k + 128)
    MFMA_STAGE(q0, q1, q2, q3, b1)
  }
  LOAD_STAGE(q0, q1, q2, q3, b1, K_DIM - 64)
  MFMA_STAGE(p0, p1, p2, p3, b0)
  MFMA_STAGE(q0, q1, q2, q3, b1)

  // epilogue: bias, L2-normalize each row, write bf16
#pragma unroll
  for (int ct = 0; ct < 8; ++ct) {
    float bv = bias[ct * 16 + l15];
#pragma unroll
    for (int j = 0; j < 4; ++j) acc[ct][j] += bv;
  }
#pragma unroll
  for (int j = 0; j < 4; ++j) {
    float ss = 0.f;
#pragma unroll
    for (int ct = 0; ct < 8; ++ct) ss += acc[ct][j] * acc[ct][j];
    ss += __shfl_xor(ss, 1);
    ss += __shfl_xor(ss, 2);
    ss += __shfl_xor(ss, 4);
    ss += __shfl_xor(ss, 8);
    float s = 1.0f / fmaxf(sqrtf(ss), 1e-12f);
    const int row = r0 + kg * 4 + j;
#pragma unroll
    for (int ct = 0; ct < 8; ++ct)
      Pn[(size_t)row * D_DIM + ct * 16 + l15] = (unsigned short)f2bf(acc[ct][j] * s);
  }
}

// ---------------- Kernel 3: banded similarity ----------------
#define TR 32
#define LROWS 136  // 50 + 32 + 50 = 132, padded (rows 132..135 zero)

__global__ __launch_bounds__(256) void k_sim(const unsigned short* __restrict__ Pn,
                                             float* __restrict__ out) {
  __shared__ unsigned short sm[LROWS * D_DIM];
  const int bb = blockIdx.x >> 6;   // batch
  const int tb = blockIdx.x & 63;   // tile within batch
  const int t0 = tb * TR;
  const int tid = threadIdx.x;

  // load rows t0-50 .. t0+81 (zero outside [0,T)), XOR-swizzled by ((i>>2)&15)
  for (int idx = tid; idx < LROWS * 16; idx += 256) {
    int i = idx >> 4, seg = idx & 15;
    int t = t0 - HWIN + i;
    uint4 val = make_uint4(0u, 0u, 0u, 0u);
    if (i < 132 && t >= 0 && t < T_LEN)
      val = *(const uint4*)(Pn + ((size_t)bb * T_LEN + t) * D_DIM + seg * 8);
    *(uint4*)&sm[i * D_DIM + ((seg ^ ((i >> 2) & 15)) << 3)] = val;
  }
  __syncthreads();

  for (int u = tid; u < TR * 26; u += 256) {
    int r = u / 26;
    int w0 = (u - r * 26) * 4;
    float acc[4] = {0.f, 0.f, 0.f, 0.f};
    const int qrow = r + HWIN;
#pragma unroll 4
    for (int dc = 0; dc < 16; ++dc) {
      uint4 q = *(const uint4*)&sm[qrow * D_DIM + ((dc ^ ((qrow >> 2) & 15)) << 3)];
      float qf0 = bflo(q.x), qf1 = bfhi(q.x), qf2 = bflo(q.y), qf3 = bfhi(q.y);
      float qf4 = bflo(q.z), qf5 = bfhi(q.z), qf6 = bflo(q.w), qf7 = bfhi(q.w);
#pragma unroll
      for (int j = 0; j < 4; ++j) {
        int wr = r + w0 + j;
        uint4 wv = *(const uint4*)&sm[wr * D_DIM + ((dc ^ ((wr >> 2) & 15)) << 3)];
        acc[j] += qf0 * bflo(wv.x) + qf1 * bfhi(wv.x) + qf2 * bflo(wv.y) + qf3 * bfhi(wv.y) +
                  qf4 * bflo(wv.z) + qf5 * bfhi(wv.z) + qf6 * bflo(wv.w) + qf7 * bfhi(wv.w);
      }
    }
    float* op = out + ((size_t)bb * T_LEN + t0 + r) * LOOKUP + w0;
#pragma unroll
    for (int j = 0; j < 4; ++j)
      if (w0 + j < LOOKUP) op[j] = acc[j];
  }
}

extern "C" void kernel_launch(void* const* d_in, const int* in_sizes, int n_in,
                              void* d_out, int out_size, void* d_ws, size_t ws_size,
                              hipStream_t stream) {
  (void)in_sizes; (void)n_in; (void)out_size; (void)ws_size;
  const float* x = (const float*)d_in[0];
  const float* W = (const float*)d_in[1];
  const float* b = (const float*)d_in[2];
  float* out = (float*)d_out;
  unsigned short* Wt = (unsigned short*)d_ws;            // 128*2048 bf16 = 512 KiB
  unsigned short* Pn = Wt + (size_t)D_DIM * K_DIM;       // 8192*128 bf16 = 2 MiB

  k_wt<<<dim3(32, 2), 256, 0, stream>>>(W, Wt);
  k_gemm<<<M_DIM / 16, 64, 0, stream>>>(x, Wt, b, Pn);
  k_sim<<<4 * (T_LEN / TR), 256, 0, stream>>>(Pn, out);
}

// Round 3
// 53.178 us; speedup vs baseline: 1.5796x; 1.3707x over previous
//
#include <hip/hip_runtime.h>
#include <hip/hip_bf16.h>

#define T_LEN 2048
#define D_DIM 128
#define K_DIM 2048
#define M_DIM 8192
#define LOOKUP 101
#define HWIN 50

typedef __attribute__((ext_vector_type(8))) short short8;
typedef __attribute__((ext_vector_type(4))) float f32x4;

static __device__ __forceinline__ unsigned int f2bf(float f) {
  unsigned int u = __float_as_uint(f);
  return (u + 0x7fffu + ((u >> 16) & 1u)) >> 16;  // RNE bf16 bits
}

static __device__ __forceinline__ short8 pack8(float4 lo, float4 hi) {
  uint4 u;
  u.x = f2bf(lo.x) | (f2bf(lo.y) << 16);
  u.y = f2bf(lo.z) | (f2bf(lo.w) << 16);
  u.z = f2bf(hi.x) | (f2bf(hi.y) << 16);
  u.w = f2bf(hi.z) | (f2bf(hi.w) << 16);
  return *(short8*)&u;
}

// ---------------- Kernel 1: W [2048][128] f32 -> Wt [128][2048] bf16 ----------------
__global__ __launch_bounds__(256) void k_wt(const float* __restrict__ W,
                                            unsigned short* __restrict__ Wt) {
  __shared__ float tile[64][65];
  const int kb = blockIdx.x;  // 0..31
  const int db = blockIdx.y;  // 0..1
  const int t = threadIdx.x;
#pragma unroll
  for (int j = 0; j < 4; ++j) {
    int idx4 = t + j * 256;          // 0..1023 float4s of the 64x64 tile
    int r = idx4 >> 4, c = (idx4 & 15) * 4;
    float4 v = *(const float4*)(W + (kb * 64 + r) * D_DIM + db * 64 + c);
    tile[r][c + 0] = v.x; tile[r][c + 1] = v.y; tile[r][c + 2] = v.z; tile[r][c + 3] = v.w;
  }
  __syncthreads();
  const int d = t >> 2, kq = t & 3;  // out row d (0..63), 16-k chunk
  unsigned int pk[8];
#pragma unroll
  for (int i = 0; i < 8; ++i) {
    unsigned int lo = f2bf(tile[kq * 16 + 2 * i][d]);
    unsigned int hi = f2bf(tile[kq * 16 + 2 * i + 1][d]);
    pk[i] = lo | (hi << 16);
  }
  unsigned short* dst = Wt + (db * 64 + d) * K_DIM + kb * 64 + kq * 16;
  *(uint4*)dst = make_uint4(pk[0], pk[1], pk[2], pk[3]);
  *(uint4*)(dst + 8) = make_uint4(pk[4], pk[5], pk[6], pk[7]);
}

// ---------------- Kernel 2: K-split GEMM, 8 waves/block, LDS reduce + fused bias/norm ----
// Block = 512 thr (8 waves) owns 16 rows. Wave w does k in [w*256, w*256+256), 8 stages of 32.
#define GW 8
#define KPW (K_DIM / GW)   // 256
#define NST (KPW / 32)     // 8

__global__ __launch_bounds__(512, 4) void k_gemm(const float* __restrict__ X,
                                                 const unsigned short* __restrict__ Wt,
                                                 const float* __restrict__ bias,
                                                 unsigned short* __restrict__ Pn) {
  __shared__ float part[GW][16][D_DIM];  // 64 KiB
  const int tid = threadIdx.x;
  const int lane = tid & 63;
  const int wv = tid >> 6;
  const int r0 = blockIdx.x * 16;
  const int l15 = lane & 15;
  const int kg = lane >> 4;

  const float* aptr = X + (size_t)(r0 + l15) * K_DIM + wv * KPW + kg * 8;
  const unsigned short* bptr = Wt + (size_t)l15 * K_DIM + wv * KPW + kg * 8;

  f32x4 acc[8];
#pragma unroll
  for (int i = 0; i < 8; ++i) acc[i] = (f32x4){0.f, 0.f, 0.f, 0.f};

  float4 a0[2], a1[2];
  short8 bb[2][8];

  a0[0] = *(const float4*)(aptr);
  a1[0] = *(const float4*)(aptr + 4);
#pragma unroll
  for (int ct = 0; ct < 8; ++ct) bb[0][ct] = *(const short8*)(bptr + (size_t)ct * 16 * K_DIM);

#pragma unroll
  for (int s = 0; s < NST; ++s) {
    const int cur = s & 1, nxt = cur ^ 1;
    if (s + 1 < NST) {
      a0[nxt] = *(const float4*)(aptr + (s + 1) * 32);
      a1[nxt] = *(const float4*)(aptr + (s + 1) * 32 + 4);
#pragma unroll
      for (int ct = 0; ct < 8; ++ct)
        bb[nxt][ct] = *(const short8*)(bptr + (size_t)ct * 16 * K_DIM + (s + 1) * 32);
    }
    short8 af = pack8(a0[cur], a1[cur]);
#pragma unroll
    for (int ct = 0; ct < 8; ++ct)
      acc[ct] = __builtin_amdgcn_mfma_f32_16x16x32_bf16(af, bb[cur][ct], acc[ct], 0, 0, 0);
  }

  // write partials to LDS
#pragma unroll
  for (int ct = 0; ct < 8; ++ct)
#pragma unroll
    for (int j = 0; j < 4; ++j)
      part[wv][kg * 4 + j][ct * 16 + l15] = acc[ct][j];
  __syncthreads();

  // reduce 8 partials + bias + row-normalize + store bf16
  const int r = tid >> 5;            // 0..15
  const int c0 = (tid & 31) * 4;     // 0..124
  float4 tot = make_float4(0.f, 0.f, 0.f, 0.f);
#pragma unroll
  for (int w = 0; w < GW; ++w) {
    float4 v = *(const float4*)&part[w][r][c0];
    tot.x += v.x; tot.y += v.y; tot.z += v.z; tot.w += v.w;
  }
  float4 bv = *(const float4*)(bias + c0);
  tot.x += bv.x; tot.y += bv.y; tot.z += bv.z; tot.w += bv.w;
  float ss = tot.x * tot.x + tot.y * tot.y + tot.z * tot.z + tot.w * tot.w;
  ss += __shfl_xor(ss, 1);
  ss += __shfl_xor(ss, 2);
  ss += __shfl_xor(ss, 4);
  ss += __shfl_xor(ss, 8);
  ss += __shfl_xor(ss, 16);
  float s = 1.0f / fmaxf(sqrtf(ss), 1e-12f);
  unsigned int p0 = f2bf(tot.x * s) | (f2bf(tot.y * s) << 16);
  unsigned int p1 = f2bf(tot.z * s) | (f2bf(tot.w * s) << 16);
  *(uint2*)(Pn + (size_t)(r0 + r) * D_DIM + c0) = make_uint2(p0, p1);
}

// ---------------- Kernel 3: banded similarity via MFMA ----------------
// Block = 256 thr (4 waves), 32 q-rows. LDS: 144 window rows (t0-50 .. t0+93, zero-padded)
// C[32 q][144 win] via 16x16x32 MFMA; banded scatter out[w = i - r] for 0<=w<=100.
#define SROWS 144

__global__ __launch_bounds__(256) void k_sim(const unsigned short* __restrict__ Pn,
                                             float* __restrict__ out) {
  __shared__ unsigned short sm[SROWS * D_DIM];  // 36 KiB, XOR-swizzled 8-short groups
  const int bb = blockIdx.x >> 6;
  const int tb = blockIdx.x & 63;
  const int t0 = tb * 32;
  const int tid = threadIdx.x;

  for (int idx = tid; idx < SROWS * 16; idx += 256) {
    int i = idx >> 4, seg = idx & 15;
    int t = t0 - HWIN + i;
    uint4 val = make_uint4(0u, 0u, 0u, 0u);
    if (t >= 0 && t < T_LEN)
      val = *(const uint4*)(Pn + ((size_t)bb * T_LEN + t) * D_DIM + seg * 8);
    *(uint4*)&sm[i * D_DIM + ((seg ^ (i & 7)) << 3)] = val;
  }
  __syncthreads();

  const int lane = tid & 63;
  const int wv = tid >> 6;
  const int l15 = lane & 15;
  const int kg = lane >> 4;
  const int rt = wv >> 1;        // q row-tile 0..1
  const int itp = wv & 1;        // window-tile parity

  // hoist A-frags (q rows) — shared across all window tiles
  short8 af[4];
  const int ia = HWIN + rt * 16 + l15;
#pragma unroll
  for (int ks = 0; ks < 4; ++ks) {
    int g = ks * 4 + kg;
    af[ks] = *(const short8*)&sm[ia * D_DIM + ((g ^ (ia & 7)) << 3)];
  }

  for (int it = itp; it < 9; it += 2) {
    f32x4 acc = (f32x4){0.f, 0.f, 0.f, 0.f};
    const int ib = it * 16 + l15;
#pragma unroll
    for (int ks = 0; ks < 4; ++ks) {
      int g = ks * 4 + kg;
      short8 bf = *(const short8*)&sm[ib * D_DIM + ((g ^ (ib & 7)) << 3)];
      acc = __builtin_amdgcn_mfma_f32_16x16x32_bf16(af[ks], bf, acc, 0, 0, 0);
    }
#pragma unroll
    for (int j = 0; j < 4; ++j) {
      int r = rt * 16 + kg * 4 + j;
      int w = ib - r;
      if (w >= 0 && w <= 100)
        out[((size_t)bb * T_LEN + t0 + r) * LOOKUP + w] = acc[j];
    }
  }
}

extern "C" void kernel_launch(void* const* d_in, const int* in_sizes, int n_in,
                              void* d_out, int out_size, void* d_ws, size_t ws_size,
                              hipStream_t stream) {
  (void)in_sizes; (void)n_in; (void)out_size; (void)ws_size;
  const float* x = (const float*)d_in[0];
  const float* W = (const float*)d_in[1];
  const float* b = (const float*)d_in[2];
  float* out = (float*)d_out;
  unsigned short* Wt = (unsigned short*)d_ws;            // 128*2048 bf16 = 512 KiB
  unsigned short* Pn = Wt + (size_t)D_DIM * K_DIM;       // 8192*128 bf16 = 2 MiB

  k_wt<<<dim3(32, 2), 256, 0, stream>>>(W, Wt);
  k_gemm<<<M_DIM / 16, 512, 0, stream>>>(x, Wt, b, Pn);
  k_sim<<<4 * (T_LEN / 32), 256, 0, stream>>>(Pn, out);
}

// Round 4
// 34.330 us; speedup vs baseline: 2.4469x; 1.5491x over previous
//
#include <hip/hip_runtime.h>
#include <hip/hip_bf16.h>

#define T_LEN 2048
#define D_DIM 128
#define K_DIM 2048
#define M_DIM 8192
#define LOOKUP 101
#define HWIN 50

typedef __attribute__((ext_vector_type(8))) short short8;
typedef __attribute__((ext_vector_type(4))) float f32x4;

static __device__ __forceinline__ unsigned int f2bf(float f) {
  unsigned int u = __float_as_uint(f);
  return (u + 0x7fffu + ((u >> 16) & 1u)) >> 16;  // RNE bf16 bits
}
static __device__ __forceinline__ float bflo(unsigned int u) { return __uint_as_float(u << 16); }
static __device__ __forceinline__ float bfhi(unsigned int u) { return __uint_as_float(u & 0xffff0000u); }

static __device__ __forceinline__ short8 pack8(float4 lo, float4 hi) {
  uint4 u;
  u.x = f2bf(lo.x) | (f2bf(lo.y) << 16);
  u.y = f2bf(lo.z) | (f2bf(lo.w) << 16);
  u.z = f2bf(hi.x) | (f2bf(hi.y) << 16);
  u.w = f2bf(hi.z) | (f2bf(hi.w) << 16);
  return *(short8*)&u;
}

typedef __attribute__((address_space(3))) unsigned char lds_uchar;
typedef const __attribute__((address_space(1))) unsigned char g_uchar;
static __device__ __forceinline__ void gll16(const void* g, void* l) {
  __builtin_amdgcn_global_load_lds((g_uchar*)g, (lds_uchar*)l, 16, 0, 0);
}

// ---- Kernel 1: W [2048][128] f32 -> Bp fragment-packed bf16 (512 KB) ----
// Bp granule (ks, ct, lane) 16B = bf16 of W[ks*32 + (lane>>4)*8 + j][ct*16 + (lane&15)], j=0..7
__global__ __launch_bounds__(256) void k_pack(const float* __restrict__ W,
                                              unsigned short* __restrict__ Bp) {
  __shared__ float sw[32][132];  // padded, 16B-aligned rows
  const int ks = blockIdx.x;     // 0..63
  const int t = threadIdx.x;
  const float* src = W + (size_t)ks * 32 * D_DIM;
#pragma unroll
  for (int j = 0; j < 4; ++j) {
    int idx = t + j * 256;       // 0..1023 float4s of 32x128
    int row = idx >> 5, c4 = idx & 31;
    float4 v = *(const float4*)(src + row * D_DIM + c4 * 4);
    *(float4*)&sw[row][c4 * 4] = v;
  }
  __syncthreads();
#pragma unroll
  for (int e = 0; e < 2; ++e) {
    int f = t * 2 + e;           // 0..511
    int ct = f >> 6, l = f & 63;
    int kr = (l >> 4) * 8, col = ct * 16 + (l & 15);
    uint4 o;
    o.x = f2bf(sw[kr + 0][col]) | (f2bf(sw[kr + 1][col]) << 16);
    o.y = f2bf(sw[kr + 2][col]) | (f2bf(sw[kr + 3][col]) << 16);
    o.z = f2bf(sw[kr + 4][col]) | (f2bf(sw[kr + 5][col]) << 16);
    o.w = f2bf(sw[kr + 6][col]) | (f2bf(sw[kr + 7][col]) << 16);
    *(uint4*)(Bp + (((size_t)(ks * 8 + ct) << 6) + l) * 8) = o;
  }
}

// ---- Kernel 2: K-split-8 GEMM, contiguous loads only, fused bias/norm ----
// 512 blocks x 512 thr (8 waves). Wave wv: rows r0..r0+15, k in [wv*256, +256) = 8 steps of 32.
// A staged per-wave via global_load_lds (1KB contiguous rows, source-XOR-swizzled granules).
__global__ __launch_bounds__(512, 4) void k_gemm(const float* __restrict__ X,
                                                 const unsigned short* __restrict__ Bp,
                                                 const float* __restrict__ bias,
                                                 unsigned short* __restrict__ Pn) {
  __shared__ __align__(16) unsigned char smem[65536];  // 8 x 8KB wave regions (A chunk / partials)
  const int tid = threadIdx.x;
  const int lane = tid & 63;
  const int wv = tid >> 6;
  const int r0 = blockIdx.x * 16;
  const int l15 = lane & 15;
  const int kg = lane >> 4;

  unsigned char* Ab = smem + wv * 8192;
  const int srow = lane >> 5;   // 0/1: which row of the instr's row-pair
  const int scol = lane & 31;   // granule within the 512B row segment

  f32x4 acc[8];
#pragma unroll
  for (int i = 0; i < 8; ++i) acc[i] = (f32x4){0.f, 0.f, 0.f, 0.f};

  for (int c = 0; c < 2; ++c) {  // 2 chunks of 128 k
    // stage: 8 instrs, each one contiguous 1KB (2 rows x 512B), lane-permuted for LDS swizzle
#pragma unroll
    for (int i = 0; i < 8; ++i) {
      int r = 2 * i + srow;
      int gsrc = scol ^ (r & 7);
      const float* src = X + (size_t)(r0 + r) * K_DIM + wv * 256 + c * 128 + gsrc * 4;
      gll16(src, Ab + i * 1024);
    }
    asm volatile("s_waitcnt vmcnt(0)" ::: "memory");
    __builtin_amdgcn_sched_barrier(0);
#pragma unroll
    for (int s = 0; s < 4; ++s) {
      int g0 = s * 8 + kg * 2;
      float4 alo = *(const float4*)(Ab + l15 * 512 + (((g0 + 0) ^ (l15 & 7)) << 4));
      float4 ahi = *(const float4*)(Ab + l15 * 512 + (((g0 + 1) ^ (l15 & 7)) << 4));
      short8 af = pack8(alo, ahi);
      int ksg = wv * 8 + c * 4 + s;
#pragma unroll
      for (int ct = 0; ct < 8; ++ct) {
        short8 bf = *(const short8*)(Bp + (((size_t)(ksg * 8 + ct) << 6) + lane) * 8);
        acc[ct] = __builtin_amdgcn_mfma_f32_16x16x32_bf16(af, bf, acc[ct], 0, 0, 0);
      }
    }
  }

  // partials into own wave region (overwrites A chunk; wave-internal in-order DS => safe)
  float* Pw = (float*)Ab;
#pragma unroll
  for (int ct = 0; ct < 8; ++ct)
#pragma unroll
    for (int j = 0; j < 4; ++j)
      Pw[(kg * 4 + j) * 128 + ct * 16 + l15] = acc[ct][j];
  __syncthreads();

  // reduce 8 partials + bias + row-normalize + store bf16
  const int row = tid >> 5;      // 0..15
  const int c4 = tid & 31;       // 4 cols each
  float4 tot = make_float4(0.f, 0.f, 0.f, 0.f);
#pragma unroll
  for (int q = 0; q < 8; ++q) {
    float4 v = *(const float4*)(smem + q * 8192 + row * 512 + c4 * 16);
    tot.x += v.x; tot.y += v.y; tot.z += v.z; tot.w += v.w;
  }
  float4 bv = *(const float4*)(bias + c4 * 4);
  tot.x += bv.x; tot.y += bv.y; tot.z += bv.z; tot.w += bv.w;
  float ss = tot.x * tot.x + tot.y * tot.y + tot.z * tot.z + tot.w * tot.w;
  ss += __shfl_xor(ss, 1);
  ss += __shfl_xor(ss, 2);
  ss += __shfl_xor(ss, 4);
  ss += __shfl_xor(ss, 8);
  ss += __shfl_xor(ss, 16);
  float sc = 1.0f / fmaxf(sqrtf(ss), 1e-12f);
  unsigned int p0 = f2bf(tot.x * sc) | (f2bf(tot.y * sc) << 16);
  unsigned int p1 = f2bf(tot.z * sc) | (f2bf(tot.w * sc) << 16);
  *(uint2*)(Pn + (size_t)(r0 + row) * D_DIM + c4 * 4) = make_uint2(p0, p1);
}

// ---------------- Kernel 3: banded similarity via MFMA ----------------
#define SROWS 144

__global__ __launch_bounds__(256) void k_sim(const unsigned short* __restrict__ Pn,
                                             float* __restrict__ out) {
  __shared__ unsigned short sm[SROWS * D_DIM];  // 36 KiB, XOR-swizzled 8-short groups
  const int bb = blockIdx.x >> 6;
  const int tb = blockIdx.x & 63;
  const int t0 = tb * 32;
  const int tid = threadIdx.x;

  for (int idx = tid; idx < SROWS * 16; idx += 256) {
    int i = idx >> 4, seg = idx & 15;
    int t = t0 - HWIN + i;
    uint4 val = make_uint4(0u, 0u, 0u, 0u);
    if (t >= 0 && t < T_LEN)
      val = *(const uint4*)(Pn + ((size_t)bb * T_LEN + t) * D_DIM + seg * 8);
    *(uint4*)&sm[i * D_DIM + ((seg ^ (i & 7)) << 3)] = val;
  }
  __syncthreads();

  const int lane = tid & 63;
  const int wv = tid >> 6;
  const int l15 = lane & 15;
  const int kg = lane >> 4;
  const int rt = wv >> 1;
  const int itp = wv & 1;

  short8 af[4];
  const int ia = HWIN + rt * 16 + l15;
#pragma unroll
  for (int ks = 0; ks < 4; ++ks) {
    int g = ks * 4 + kg;
    af[ks] = *(const short8*)&sm[ia * D_DIM + ((g ^ (ia & 7)) << 3)];
  }

  for (int it = itp; it < 9; it += 2) {
    f32x4 acc = (f32x4){0.f, 0.f, 0.f, 0.f};
    const int ib = it * 16 + l15;
#pragma unroll
    for (int ks = 0; ks < 4; ++ks) {
      int g = ks * 4 + kg;
      short8 bf = *(const short8*)&sm[ib * D_DIM + ((g ^ (ib & 7)) << 3)];
      acc = __builtin_amdgcn_mfma_f32_16x16x32_bf16(af[ks], bf, acc, 0, 0, 0);
    }
#pragma unroll
    for (int j = 0; j < 4; ++j) {
      int r = rt * 16 + kg * 4 + j;
      int w = ib - r;
      if (w >= 0 && w <= 100)
        out[((size_t)bb * T_LEN + t0 + r) * LOOKUP + w] = acc[j];
    }
  }
}

extern "C" void kernel_launch(void* const* d_in, const int* in_sizes, int n_in,
                              void* d_out, int out_size, void* d_ws, size_t ws_size,
                              hipStream_t stream) {
  (void)in_sizes; (void)n_in; (void)out_size; (void)ws_size;
  const float* x = (const float*)d_in[0];
  const float* W = (const float*)d_in[1];
  const float* b = (const float*)d_in[2];
  float* out = (float*)d_out;
  unsigned short* Bp = (unsigned short*)d_ws;            // 512 KiB fragment-packed W
  unsigned short* Pn = Bp + (size_t)D_DIM * K_DIM;       // 8192*128 bf16 = 2 MiB

  k_pack<<<64, 256, 0, stream>>>(W, Bp);
  k_gemm<<<M_DIM / 16, 512, 0, stream>>>(x, Bp, b, Pn);
  k_sim<<<4 * (T_LEN / 32), 256, 0, stream>>>(Pn, out);
}

// Round 5
// 33.655 us; speedup vs baseline: 2.4959x; 1.0200x over previous
//
#include <hip/hip_runtime.h>
#include <hip/hip_bf16.h>

#define T_LEN 2048
#define D_DIM 128
#define K_DIM 2048
#define M_DIM 8192
#define LOOKUP 101
#define HWIN 50

typedef __attribute__((ext_vector_type(8))) short short8;
typedef __attribute__((ext_vector_type(4))) float f32x4;

static __device__ __forceinline__ unsigned int f2bf(float f) {
  unsigned int u = __float_as_uint(f);
  return (u + 0x7fffu + ((u >> 16) & 1u)) >> 16;  // RNE bf16 bits
}

static __device__ __forceinline__ short8 pack8(float4 lo, float4 hi) {
  uint4 u;
  u.x = f2bf(lo.x) | (f2bf(lo.y) << 16);
  u.y = f2bf(lo.z) | (f2bf(lo.w) << 16);
  u.z = f2bf(hi.x) | (f2bf(hi.y) << 16);
  u.w = f2bf(hi.z) | (f2bf(hi.w) << 16);
  return *(short8*)&u;
}

typedef __attribute__((address_space(3))) unsigned char lds_uchar;
typedef const __attribute__((address_space(1))) unsigned char g_uchar;
static __device__ __forceinline__ void gll16(const void* g, void* l) {
  __builtin_amdgcn_global_load_lds((g_uchar*)g, (lds_uchar*)l, 16, 0, 0);
}
#define SB() __builtin_amdgcn_sched_barrier(0)

// ---- Kernel 1: W [2048][128] f32 -> Bp fragment-packed bf16 (512 KB) ----
// Bp granule (ks, ct, lane) 16B = bf16 of W[ks*32 + (lane>>4)*8 + j][ct*16 + (lane&15)], j=0..7
__global__ __launch_bounds__(256) void k_pack(const float* __restrict__ W,
                                              unsigned short* __restrict__ Bp) {
  __shared__ float sw[32][132];
  const int ks = blockIdx.x;  // 0..63
  const int t = threadIdx.x;
  const float* src = W + (size_t)ks * 32 * D_DIM;
#pragma unroll
  for (int j = 0; j < 4; ++j) {
    int idx = t + j * 256;
    int row = idx >> 5, c4 = idx & 31;
    float4 v = *(const float4*)(src + row * D_DIM + c4 * 4);
    *(float4*)&sw[row][c4 * 4] = v;
  }
  __syncthreads();
#pragma unroll
  for (int e = 0; e < 2; ++e) {
    int f = t * 2 + e;
    int ct = f >> 6, l = f & 63;
    int kr = (l >> 4) * 8, col = ct * 16 + (l & 15);
    uint4 o;
    o.x = f2bf(sw[kr + 0][col]) | (f2bf(sw[kr + 1][col]) << 16);
    o.y = f2bf(sw[kr + 2][col]) | (f2bf(sw[kr + 3][col]) << 16);
    o.z = f2bf(sw[kr + 4][col]) | (f2bf(sw[kr + 5][col]) << 16);
    o.w = f2bf(sw[kr + 6][col]) | (f2bf(sw[kr + 7][col]) << 16);
    *(uint4*)(Bp + (((size_t)(ks * 8 + ct) << 6) + l) * 8) = o;
  }
}

// ---- Kernel 2: K-split-8 GEMM, counted-vmcnt pipeline, fused bias/norm ----
// 512 blocks x 512 thr (8 waves). Wave wv: rows r0..r0+15, k in [wv*256,+256) = 8 steps of 32,
// grouped as 4 chunks of 64k. A double-buffered in LDS (2x4KB/wave) via gll16 with
// source-XOR pre-swizzle; B prefetched one step ahead into named register sets.
__global__ __launch_bounds__(512, 4) void k_gemm(const float* __restrict__ X,
                                                 const unsigned short* __restrict__ Bp,
                                                 const float* __restrict__ bias,
                                                 unsigned short* __restrict__ Pn) {
  __shared__ __align__(16) unsigned char smem[65536];  // 8 waves x 8KB (2 A-bufs / partials)
  const int tid = threadIdx.x;
  const int lane = tid & 63;
  const int wv = tid >> 6;
  const int r0 = blockIdx.x * 16;
  const int l15 = lane & 15;
  const int kg = lane >> 4;

  unsigned char* Ab = smem + wv * 8192;

  f32x4 acc[8];
#pragma unroll
  for (int i = 0; i < 8; ++i) acc[i] = (f32x4){0.f, 0.f, 0.f, 0.f};

  short8 bA0, bA1, bA2, bA3, bA4, bA5, bA6, bA7;
  short8 bB0, bB1, bB2, bB3, bB4, bB5, bB6, bB7;

  // stage chunk c (64 k-cols, 16 rows x 256B = 4KB) into buf (c&1); 4 contiguous 1KB gll16
  auto stage = [&](int c) {
#pragma unroll
    for (int i = 0; i < 4; ++i) {
      int r = i * 4 + (lane >> 4);
      int gsrc = (lane & 15) ^ (r & 7);
      const float* src = X + (size_t)(r0 + r) * K_DIM + wv * 256 + c * 64 + gsrc * 4;
      gll16(src, Ab + (c & 1) * 4096 + i * 1024);
    }
  };
#define LOADB(P, step)                                                                  \
  {                                                                                     \
    int ksg = wv * 8 + (step);                                                          \
    P##0 = *(const short8*)(Bp + ((size_t)(ksg * 8 + 0) * 64 + lane) * 8);              \
    P##1 = *(const short8*)(Bp + ((size_t)(ksg * 8 + 1) * 64 + lane) * 8);              \
    P##2 = *(const short8*)(Bp + ((size_t)(ksg * 8 + 2) * 64 + lane) * 8);              \
    P##3 = *(const short8*)(Bp + ((size_t)(ksg * 8 + 3) * 64 + lane) * 8);              \
    P##4 = *(const short8*)(Bp + ((size_t)(ksg * 8 + 4) * 64 + lane) * 8);              \
    P##5 = *(const short8*)(Bp + ((size_t)(ksg * 8 + 5) * 64 + lane) * 8);              \
    P##6 = *(const short8*)(Bp + ((size_t)(ksg * 8 + 6) * 64 + lane) * 8);              \
    P##7 = *(const short8*)(Bp + ((size_t)(ksg * 8 + 7) * 64 + lane) * 8);              \
  }
#define DOSTEP(P, c, s)                                                                  \
  {                                                                                      \
    int g0 = (s)*8 + kg * 2;                                                             \
    const unsigned char* ab = Ab + ((c)&1) * 4096 + l15 * 256;                           \
    float4 alo = *(const float4*)(ab + (((g0 + 0) ^ (l15 & 7)) << 4));                   \
    float4 ahi = *(const float4*)(ab + (((g0 + 1) ^ (l15 & 7)) << 4));                   \
    short8 af = pack8(alo, ahi);                                                         \
    acc[0] = __builtin_amdgcn_mfma_f32_16x16x32_bf16(af, P##0, acc[0], 0, 0, 0);         \
    acc[1] = __builtin_amdgcn_mfma_f32_16x16x32_bf16(af, P##1, acc[1], 0, 0, 0);         \
    acc[2] = __builtin_amdgcn_mfma_f32_16x16x32_bf16(af, P##2, acc[2], 0, 0, 0);         \
    acc[3] = __builtin_amdgcn_mfma_f32_16x16x32_bf16(af, P##3, acc[3], 0, 0, 0);         \
    acc[4] = __builtin_amdgcn_mfma_f32_16x16x32_bf16(af, P##4, acc[4], 0, 0, 0);         \
    acc[5] = __builtin_amdgcn_mfma_f32_16x16x32_bf16(af, P##5, acc[5], 0, 0, 0);         \
    acc[6] = __builtin_amdgcn_mfma_f32_16x16x32_bf16(af, P##6, acc[6], 0, 0, 0);         \
    acc[7] = __builtin_amdgcn_mfma_f32_16x16x32_bf16(af, P##7, acc[7], 0, 0, 0);         \
  }

  // prologue: outstanding = [stage(0):4, bA:8]
  stage(0);
  SB();
  LOADB(bA, 0);
  SB();

  for (int c = 0; c < 3; ++c) {
    LOADB(bB, 2 * c + 1);          // outstanding: stage(c)4, bA8, bB8
    SB();
    stage(c + 1);                  // +4 -> 24
    SB();
    asm volatile("s_waitcnt vmcnt(12)" ::: "memory");  // completes stage(c)+bA
    SB();
    DOSTEP(bA, c, 0);
    SB();
    LOADB(bA, 2 * c + 2);          // outstanding: bB8, stage(c+1)4, bA8 = 20
    SB();
    asm volatile("s_waitcnt vmcnt(12)" ::: "memory");  // completes bB
    SB();
    DOSTEP(bB, c, 1);
    SB();
  }
  // c=3 peeled: entry outstanding = [stage(3):4, bA:8]
  LOADB(bB, 7);
  SB();
  asm volatile("s_waitcnt vmcnt(8)" ::: "memory");  // completes stage(3)+bA
  SB();
  DOSTEP(bA, 3, 0);
  SB();
  asm volatile("s_waitcnt vmcnt(0)" ::: "memory");  // completes bB
  SB();
  DOSTEP(bB, 3, 1);

  // partials into own wave region (overwrites A bufs; wave-internal in-order DS => safe)
  float* Pw = (float*)Ab;
#pragma unroll
  for (int ct = 0; ct < 8; ++ct)
#pragma unroll
    for (int j = 0; j < 4; ++j)
      Pw[(kg * 4 + j) * 128 + ct * 16 + l15] = acc[ct][j];
  __syncthreads();

  // reduce 8 partials + bias + row-normalize + store bf16
  const int row = tid >> 5;
  const int c4 = tid & 31;
  float4 tot = make_float4(0.f, 0.f, 0.f, 0.f);
#pragma unroll
  for (int q = 0; q < 8; ++q) {
    float4 v = *(const float4*)(smem + q * 8192 + row * 512 + c4 * 16);
    tot.x += v.x; tot.y += v.y; tot.z += v.z; tot.w += v.w;
  }
  float4 bv = *(const float4*)(bias + c4 * 4);
  tot.x += bv.x; tot.y += bv.y; tot.z += bv.z; tot.w += bv.w;
  float ss = tot.x * tot.x + tot.y * tot.y + tot.z * tot.z + tot.w * tot.w;
  ss += __shfl_xor(ss, 1);
  ss += __shfl_xor(ss, 2);
  ss += __shfl_xor(ss, 4);
  ss += __shfl_xor(ss, 8);
  ss += __shfl_xor(ss, 16);
  float sc = 1.0f / fmaxf(sqrtf(ss), 1e-12f);
  unsigned int p0 = f2bf(tot.x * sc) | (f2bf(tot.y * sc) << 16);
  unsigned int p1 = f2bf(tot.z * sc) | (f2bf(tot.w * sc) << 16);
  *(uint2*)(Pn + (size_t)(r0 + row) * D_DIM + c4 * 4) = make_uint2(p0, p1);
}

// ---------------- Kernel 3: banded similarity via MFMA ----------------
#define SROWS 144

__global__ __launch_bounds__(256) void k_sim(const unsigned short* __restrict__ Pn,
                                             float* __restrict__ out) {
  __shared__ unsigned short sm[SROWS * D_DIM];  // 36 KiB, XOR-swizzled 8-short groups
  const int bb = blockIdx.x >> 6;
  const int tb = blockIdx.x & 63;
  const int t0 = tb * 32;
  const int tid = threadIdx.x;

  for (int idx = tid; idx < SROWS * 16; idx += 256) {
    int i = idx >> 4, seg = idx & 15;
    int t = t0 - HWIN + i;
    uint4 val = make_uint4(0u, 0u, 0u, 0u);
    if (t >= 0 && t < T_LEN)
      val = *(const uint4*)(Pn + ((size_t)bb * T_LEN + t) * D_DIM + seg * 8);
    *(uint4*)&sm[i * D_DIM + ((seg ^ (i & 7)) << 3)] = val;
  }
  __syncthreads();

  const int lane = tid & 63;
  const int wv = tid >> 6;
  const int l15 = lane & 15;
  const int kg = lane >> 4;
  const int rt = wv >> 1;
  const int itp = wv & 1;

  short8 af[4];
  const int ia = HWIN + rt * 16 + l15;
#pragma unroll
  for (int ks = 0; ks < 4; ++ks) {
    int g = ks * 4 + kg;
    af[ks] = *(const short8*)&sm[ia * D_DIM + ((g ^ (ia & 7)) << 3)];
  }

  for (int it = itp; it < 9; it += 2) {
    f32x4 acc = (f32x4){0.f, 0.f, 0.f, 0.f};
    const int ib = it * 16 + l15;
#pragma unroll
    for (int ks = 0; ks < 4; ++ks) {
      int g = ks * 4 + kg;
      short8 bf = *(const short8*)&sm[ib * D_DIM + ((g ^ (ib & 7)) << 3)];
      acc = __builtin_amdgcn_mfma_f32_16x16x32_bf16(af[ks], bf, acc, 0, 0, 0);
    }
#pragma unroll
    for (int j = 0; j < 4; ++j) {
      int r = rt * 16 + kg * 4 + j;
      int w = ib - r;
      if (w >= 0 && w <= 100)
        out[((size_t)bb * T_LEN + t0 + r) * LOOKUP + w] = acc[j];
    }
  }
}

extern "C" void kernel_launch(void* const* d_in, const int* in_sizes, int n_in,
                              void* d_out, int out_size, void* d_ws, size_t ws_size,
                              hipStream_t stream) {
  (void)in_sizes; (void)n_in; (void)out_size; (void)ws_size;
  const float* x = (const float*)d_in[0];
  const float* W = (const float*)d_in[1];
  const float* b = (const float*)d_in[2];
  float* out = (float*)d_out;
  unsigned short* Bp = (unsigned short*)d_ws;            // 512 KiB fragment-packed W
  unsigned short* Pn = Bp + (size_t)D_DIM * K_DIM;       // 8192*128 bf16 = 2 MiB

  k_pack<<<64, 256, 0, stream>>>(W, Bp);
  k_gemm<<<M_DIM / 16, 512, 0, stream>>>(x, Bp, b, Pn);
  k_sim<<<4 * (T_LEN / 32), 256, 0, stream>>>(Pn, out);
}